// Round 2
// baseline (586.909 us; speedup 1.0000x reference)
//
#include <hip/hip_runtime.h>
#include <math.h>

// Problem constants (from reference)
#define NN 100000
#define NE 1600000
#define D 64
#define DE 16
#define NEG_SLOPE 0.01f
#define LN_EPS 1e-5f

// ---------- helpers ----------
__device__ __forceinline__ float wsum(float v) {
    #pragma unroll
    for (int d = 32; d > 0; d >>= 1) v += __shfl_xor(v, d, 64);
    return v;
}
__device__ __forceinline__ float wmaxr(float v) {
    #pragma unroll
    for (int d = 32; d > 0; d >>= 1) v = fmaxf(v, __shfl_xor(v, d, 64));
    return v;
}

// ---------- K1: per-node  x_t = x @ W2^T, ar = x.att_r, al = x.v1 ----------
__global__ __launch_bounds__(256) void k1_node(
        const float* __restrict__ x,
        const float* __restrict__ W1,
        const float* __restrict__ W2,
        const float* __restrict__ att_l,
        const float* __restrict__ att_r,
        float* __restrict__ x_t,
        float* __restrict__ ar,
        float* __restrict__ al)
{
    const int lane = threadIdx.x & 63;
    const int wid  = (blockIdx.x * blockDim.x + threadIdx.x) >> 6;
    const int nw   = (gridDim.x * blockDim.x) >> 6;

    // W2 row `lane` -> 64 VGPRs (vectorized 16B loads)
    float w2r[D];
    {
        const float4* wr = reinterpret_cast<const float4*>(W2 + (size_t)lane * D);
        #pragma unroll
        for (int q = 0; q < 16; ++q) {
            float4 p = wr[q];
            w2r[q * 4 + 0] = p.x;
            w2r[q * 4 + 1] = p.y;
            w2r[q * 4 + 2] = p.z;
            w2r[q * 4 + 3] = p.w;
        }
    }
    // v1[lane] = sum_i att_l[i] * W1[i][lane]   (W1 is [64, 80] row-major)
    const float attr_j = att_r[lane];
    const float alv    = att_l[lane];
    float v1j = 0.f;
    for (int i = 0; i < D; ++i) {
        float ali = __shfl(alv, i, 64);
        v1j = fmaf(ali, W1[i * 80 + lane], v1j);
    }

    for (int n = wid; n < NN; n += nw) {
        float xj = x[(size_t)n * D + lane];
        float acc = 0.f;
        #pragma unroll
        for (int k = 0; k < D; ++k)
            acc = fmaf(__shfl(xj, k, 64), w2r[k], acc);
        x_t[(size_t)n * D + lane] = acc;
        float sr = wsum(xj * attr_j);
        float sl = wsum(xj * v1j);
        if (lane == 0) { ar[n] = sr; al[n] = sl; }
    }
}

// ---------- K2: per-edge  e = leaky(al[src] + ar[dst] + ea.v2), counts[dst]++ ----------
__global__ __launch_bounds__(256) void k2_edge(
        const float* __restrict__ eattr,
        const float* __restrict__ W1,
        const float* __restrict__ att_l,
        const int* __restrict__ src,
        const int* __restrict__ dst,
        const float* __restrict__ al,
        const float* __restrict__ ar,
        float* __restrict__ e_buf,
        int* __restrict__ counts)
{
    __shared__ float als[D];
    __shared__ float v2s[DE];
    const int t = threadIdx.x;
    if (t < D) als[t] = att_l[t];
    __syncthreads();
    if (t < DE) {
        float a = 0.f;
        for (int i = 0; i < D; ++i)
            a = fmaf(als[i], W1[i * 80 + D + t], a);
        v2s[t] = a;
    }
    __syncthreads();
    float v2r[DE];
    #pragma unroll
    for (int j = 0; j < DE; ++j) v2r[j] = v2s[j];

    const int e = blockIdx.x * blockDim.x + t;   // grid sized exactly NE/256
    int s = src[e], d = dst[e];
    float acc = al[s] + ar[d];
    const float4* ep = reinterpret_cast<const float4*>(eattr + (size_t)e * DE);
    #pragma unroll
    for (int q = 0; q < 4; ++q) {
        float4 p = ep[q];
        acc = fmaf(p.x, v2r[4 * q + 0], acc);
        acc = fmaf(p.y, v2r[4 * q + 1], acc);
        acc = fmaf(p.z, v2r[4 * q + 2], acc);
        acc = fmaf(p.w, v2r[4 * q + 3], acc);
    }
    float ev = acc > 0.f ? acc : NEG_SLOPE * acc;
    e_buf[e] = ev;
    atomicAdd(&counts[d], 1);
}

// ---------- K3: segment base allocation (wave scan + 1 atomic/wave) ----------
__global__ __launch_bounds__(256) void k3_alloc(
        const int* __restrict__ counts,
        int* __restrict__ basev,
        int* __restrict__ total)
{
    const int n = blockIdx.x * blockDim.x + threadIdx.x;
    const int lane = threadIdx.x & 63;
    int c = (n < NN) ? counts[n] : 0;
    int inc = c;
    #pragma unroll
    for (int dlt = 1; dlt < 64; dlt <<= 1) {
        int o = __shfl_up(inc, dlt, 64);
        if (lane >= dlt) inc += o;
    }
    int wtot = __shfl(inc, 63, 64);
    int wbase = 0;
    if (lane == 63) wbase = atomicAdd(total, wtot);
    wbase = __shfl(wbase, 63, 64);
    if (n < NN) basev[n] = wbase + inc - c;
}

// ---------- K4: scatter edges into dst-grouped arrays ----------
__global__ __launch_bounds__(256) void k4_scatter(
        const int* __restrict__ src,
        const int* __restrict__ dst,
        const float* __restrict__ e_buf,
        const int* __restrict__ basev,
        int* __restrict__ cursor,
        float* __restrict__ e_srt,
        int* __restrict__ src_srt)
{
    const int e = blockIdx.x * blockDim.x + threadIdx.x;  // exact grid
    int d = dst[e];
    int pos = basev[d] + atomicAdd(&cursor[d], 1);
    e_srt[pos] = e_buf[e];
    src_srt[pos] = src[e];
}

// ---------- K5: per-node softmax + weighted aggregation + bias + LayerNorm ----------
__global__ __launch_bounds__(256) void k5_agg(
        const float* __restrict__ x_t,
        const float* __restrict__ e_srt,
        const int* __restrict__ src_srt,
        const int* __restrict__ basev,
        const int* __restrict__ counts,
        const float* __restrict__ bias,
        const float* __restrict__ gamma,
        const float* __restrict__ beta,
        float* __restrict__ out)
{
    const int wid  = (blockIdx.x * blockDim.x + threadIdx.x) >> 6;  // node
    const int lane = threadIdx.x & 63;                              // feature
    if (wid >= NN) return;
    const int base = basev[wid];
    const int cnt  = counts[wid];

    float m = -1e30f;
    for (int i = lane; i < cnt; i += 64) m = fmaxf(m, e_srt[base + i]);
    m = wmaxr(m);
    float ssum = 0.f;
    for (int i = lane; i < cnt; i += 64) ssum += __expf(e_srt[base + i] - m);
    ssum = wsum(ssum);
    const float inv = (cnt > 0) ? 1.f / ssum : 0.f;

    float acc = 0.f;
    for (int c0 = 0; c0 < cnt; c0 += 64) {
        int i = c0 + lane;
        float av = 0.f; int sv = 0;
        if (i < cnt) {
            av = __expf(e_srt[base + i] - m) * inv;
            sv = src_srt[base + i];
        }
        int lim = min(64, cnt - c0);
        for (int j = 0; j < lim; ++j) {
            float aj = __shfl(av, j, 64);
            int   sj = __shfl(sv, j, 64);
            acc = fmaf(aj, x_t[(size_t)sj * D + lane], acc);
        }
    }
    float h  = acc + bias[lane];
    float mu = wsum(h) * (1.f / 64.f);
    float dd = h - mu;
    float var = wsum(dd * dd) * (1.f / 64.f);
    float o = dd * rsqrtf(var + LN_EPS) * gamma[lane] + beta[lane];
    out[(size_t)wid * D + lane] = o;
}

// ---------- launch ----------
extern "C" void kernel_launch(void* const* d_in, const int* in_sizes, int n_in,
                              void* d_out, int out_size, void* d_ws, size_t ws_size,
                              hipStream_t stream) {
    const float* x     = (const float*)d_in[0];
    const float* eattr = (const float*)d_in[1];
    const float* W1    = (const float*)d_in[2];
    const float* W2    = (const float*)d_in[3];
    const float* att_l = (const float*)d_in[4];
    const float* att_r = (const float*)d_in[5];
    const float* bias  = (const float*)d_in[6];
    const float* gamma = (const float*)d_in[7];
    const float* beta  = (const float*)d_in[8];
    const int* src = (const int*)d_in[9];
    const int* dst = (const int*)d_in[10];
    float* out = (float*)d_out;

    // workspace layout (256B aligned chunks), ~47 MB total
    char* p = (char*)d_ws;
    size_t off = 0;
    auto take = [&](size_t bytes) {
        void* q = p + off;
        off += (bytes + 255) & ~(size_t)255;
        return q;
    };
    float* x_t   = (float*)take((size_t)NN * D * 4);
    float* ar    = (float*)take((size_t)NN * 4);
    float* al    = (float*)take((size_t)NN * 4);
    float* e_buf = (float*)take((size_t)NE * 4);
    float* e_srt = (float*)take((size_t)NE * 4);
    int*  src_srt= (int*)  take((size_t)NE * 4);
    int*  basev  = (int*)  take((size_t)NN * 4);
    // zero-init region: counts, cursor, total (contiguous)
    size_t zero_begin = off;
    int*  counts = (int*)  take((size_t)NN * 4);
    int*  cursor = (int*)  take((size_t)NN * 4);
    int*  total  = (int*)  take(256);
    size_t zero_len = off - zero_begin;

    hipMemsetAsync(counts, 0, zero_len, stream);

    k1_node<<<2048, 256, 0, stream>>>(x, W1, W2, att_l, att_r, x_t, ar, al);
    k2_edge<<<NE / 256, 256, 0, stream>>>(eattr, W1, att_l, src, dst, al, ar, e_buf, counts);
    k3_alloc<<<(NN + 255) / 256, 256, 0, stream>>>(counts, basev, total);
    k4_scatter<<<NE / 256, 256, 0, stream>>>(src, dst, e_buf, basev, cursor, e_srt, src_srt);
    k5_agg<<<(NN * D) / 256, 256, 0, stream>>>(x_t, e_srt, src_srt, basev, counts,
                                               bias, gamma, beta, out);
}

// Round 3
// 516.614 us; speedup vs baseline: 1.1361x; 1.1361x over previous
//
#include <hip/hip_runtime.h>
#include <math.h>

// Problem constants (from reference)
#define NN 100000
#define NE 1600000
#define D 64
#define DE 16
#define NEG_SLOPE 0.01f
#define LN_EPS 1e-5f

// ---------- helpers ----------
__device__ __forceinline__ float wsum(float v) {
    #pragma unroll
    for (int d = 32; d > 0; d >>= 1) v += __shfl_xor(v, d, 64);
    return v;
}
__device__ __forceinline__ float wmaxr(float v) {
    #pragma unroll
    for (int d = 32; d > 0; d >>= 1) v = fmaxf(v, __shfl_xor(v, d, 64));
    return v;
}
__device__ __forceinline__ unsigned int f2u(float f) {
    union { float f; unsigned int u; } v; v.f = f; return v.u;
}
__device__ __forceinline__ float u2f(unsigned int u) {
    union { unsigned int u; float f; } v; v.u = u; return v.f;
}

// ---------- K1: per-node  x_t = x @ W2^T, ar = x.att_r, al = x.v1 ----------
__global__ __launch_bounds__(256) void k1_node(
        const float* __restrict__ x,
        const float* __restrict__ W1,
        const float* __restrict__ W2,
        const float* __restrict__ att_l,
        const float* __restrict__ att_r,
        float* __restrict__ x_t,
        float* __restrict__ ar,
        float* __restrict__ al)
{
    const int lane = threadIdx.x & 63;
    const int wid  = (blockIdx.x * blockDim.x + threadIdx.x) >> 6;
    const int nw   = (gridDim.x * blockDim.x) >> 6;

    // W2 row `lane` -> 64 VGPRs
    float w2r[D];
    {
        const float4* wr = reinterpret_cast<const float4*>(W2 + (size_t)lane * D);
        #pragma unroll
        for (int q = 0; q < 16; ++q) {
            float4 p = wr[q];
            w2r[q * 4 + 0] = p.x; w2r[q * 4 + 1] = p.y;
            w2r[q * 4 + 2] = p.z; w2r[q * 4 + 3] = p.w;
        }
    }
    // v1[lane] = sum_i att_l[i] * W1[i][lane]   (W1 is [64, 80] row-major)
    const float attr_j = att_r[lane];
    const float alv    = att_l[lane];
    float v1j = 0.f;
    for (int i = 0; i < D; ++i) {
        float ali = __shfl(alv, i, 64);
        v1j = fmaf(ali, W1[i * 80 + lane], v1j);
    }

    for (int n = wid; n < NN; n += nw) {
        float xj = x[(size_t)n * D + lane];
        float acc = 0.f;
        #pragma unroll
        for (int k = 0; k < D; ++k)
            acc = fmaf(__shfl(xj, k, 64), w2r[k], acc);
        x_t[(size_t)n * D + lane] = acc;
        float sr = wsum(xj * attr_j);
        float sl = wsum(xj * v1j);
        if (lane == 0) { ar[n] = sr; al[n] = sl; }
    }
}

// ---------- K2: per-edge degree histogram ----------
__global__ __launch_bounds__(256) void k2_count(
        const int* __restrict__ dst,
        int* __restrict__ counts)
{
    const int e = blockIdx.x * blockDim.x + threadIdx.x;  // exact grid
    atomicAdd(&counts[dst[e]], 1);
}

// ---------- K3: segment base allocation (wave scan + 1 atomic/wave) ----------
__global__ __launch_bounds__(256) void k3_alloc(
        const int* __restrict__ counts,
        int* __restrict__ basev,
        int* __restrict__ total)
{
    const int n = blockIdx.x * blockDim.x + threadIdx.x;
    const int lane = threadIdx.x & 63;
    int c = (n < NN) ? counts[n] : 0;
    int inc = c;
    #pragma unroll
    for (int dlt = 1; dlt < 64; dlt <<= 1) {
        int o = __shfl_up(inc, dlt, 64);
        if (lane >= dlt) inc += o;
    }
    int wtot = __shfl(inc, 63, 64);
    int wbase = 0;
    if (lane == 63) wbase = atomicAdd(total, wtot);
    wbase = __shfl(wbase, 63, 64);
    if (n < NN) basev[n] = wbase + inc - c;
}

// ---------- K4 (fused): e = leaky(al[src]+ar[dst]+ea.v2); scatter packed (e,src) ----------
__global__ __launch_bounds__(256) void k4_fused(
        const float* __restrict__ eattr,
        const float* __restrict__ W1,
        const float* __restrict__ att_l,
        const int* __restrict__ src,
        const int* __restrict__ dst,
        const float* __restrict__ al,
        const float* __restrict__ ar,
        const int* __restrict__ basev,
        int* __restrict__ cursor,
        unsigned long long* __restrict__ e_pack)
{
    __shared__ float als[D];
    __shared__ float v2s[DE];
    const int t = threadIdx.x;
    if (t < D) als[t] = att_l[t];
    __syncthreads();
    if (t < DE) {
        float a = 0.f;
        for (int i = 0; i < D; ++i)
            a = fmaf(als[i], W1[i * 80 + D + t], a);
        v2s[t] = a;
    }
    __syncthreads();
    float v2r[DE];
    #pragma unroll
    for (int j = 0; j < DE; ++j) v2r[j] = v2s[j];

    const int e = blockIdx.x * blockDim.x + t;   // exact grid NE/256
    int s = src[e], d = dst[e];
    float acc = al[s] + ar[d];
    const float4* ep = reinterpret_cast<const float4*>(eattr + (size_t)e * DE);
    #pragma unroll
    for (int q = 0; q < 4; ++q) {
        float4 p = ep[q];
        acc = fmaf(p.x, v2r[4 * q + 0], acc);
        acc = fmaf(p.y, v2r[4 * q + 1], acc);
        acc = fmaf(p.z, v2r[4 * q + 2], acc);
        acc = fmaf(p.w, v2r[4 * q + 3], acc);
    }
    float ev = acc > 0.f ? acc : NEG_SLOPE * acc;
    int pos = basev[d] + atomicAdd(&cursor[d], 1);
    unsigned long long pk = ((unsigned long long)(unsigned int)s << 32) |
                            (unsigned long long)f2u(ev);
    e_pack[pos] = pk;
}

// ---------- K5: per-node softmax + weighted aggregation + bias + LayerNorm ----------
__global__ __launch_bounds__(256) void k5_agg(
        const float* __restrict__ x_t,
        const unsigned long long* __restrict__ e_pack,
        const int* __restrict__ basev,
        const int* __restrict__ counts,
        const float* __restrict__ bias,
        const float* __restrict__ gamma,
        const float* __restrict__ beta,
        float* __restrict__ out)
{
    const int wid  = (blockIdx.x * blockDim.x + threadIdx.x) >> 6;  // node
    const int lane = threadIdx.x & 63;                              // feature
    if (wid >= NN) return;
    const int base = basev[wid];
    const int cnt  = counts[wid];

    float m = -1e30f;
    for (int i = lane; i < cnt; i += 64)
        m = fmaxf(m, u2f((unsigned int)e_pack[base + i]));
    m = wmaxr(m);
    float ssum = 0.f;
    for (int i = lane; i < cnt; i += 64)
        ssum += __expf(u2f((unsigned int)e_pack[base + i]) - m);
    ssum = wsum(ssum);
    const float inv = (cnt > 0) ? 1.f / ssum : 0.f;

    float acc0 = 0.f, acc1 = 0.f;
    for (int c0 = 0; c0 < cnt; c0 += 64) {
        int i = c0 + lane;
        float av = 0.f; int sv = 0;
        if (i < cnt) {
            unsigned long long pk = e_pack[base + i];
            av = __expf(u2f((unsigned int)pk) - m) * inv;
            sv = (int)(pk >> 32);
        }
        int lim = min(64, cnt - c0);
        int j = 0;
        for (; j + 1 < lim; j += 2) {
            float aj0 = __shfl(av, j, 64);
            int   sj0 = __shfl(sv, j, 64);
            float aj1 = __shfl(av, j + 1, 64);
            int   sj1 = __shfl(sv, j + 1, 64);
            float v0 = x_t[(size_t)sj0 * D + lane];
            float v1 = x_t[(size_t)sj1 * D + lane];
            acc0 = fmaf(aj0, v0, acc0);
            acc1 = fmaf(aj1, v1, acc1);
        }
        if (j < lim) {
            float aj = __shfl(av, j, 64);
            int   sj = __shfl(sv, j, 64);
            acc0 = fmaf(aj, x_t[(size_t)sj * D + lane], acc0);
        }
    }
    float h  = acc0 + acc1 + bias[lane];
    float mu = wsum(h) * (1.f / 64.f);
    float dd = h - mu;
    float var = wsum(dd * dd) * (1.f / 64.f);
    float o = dd * rsqrtf(var + LN_EPS) * gamma[lane] + beta[lane];
    out[(size_t)wid * D + lane] = o;
}

// ---------- launch ----------
extern "C" void kernel_launch(void* const* d_in, const int* in_sizes, int n_in,
                              void* d_out, int out_size, void* d_ws, size_t ws_size,
                              hipStream_t stream) {
    const float* x     = (const float*)d_in[0];
    const float* eattr = (const float*)d_in[1];
    const float* W1    = (const float*)d_in[2];
    const float* W2    = (const float*)d_in[3];
    const float* att_l = (const float*)d_in[4];
    const float* att_r = (const float*)d_in[5];
    const float* bias  = (const float*)d_in[6];
    const float* gamma = (const float*)d_in[7];
    const float* beta  = (const float*)d_in[8];
    const int* src = (const int*)d_in[9];
    const int* dst = (const int*)d_in[10];
    float* out = (float*)d_out;

    // workspace layout (256B aligned chunks)
    char* p = (char*)d_ws;
    size_t off = 0;
    auto take = [&](size_t bytes) {
        void* q = p + off;
        off += (bytes + 255) & ~(size_t)255;
        return q;
    };
    float* x_t   = (float*)take((size_t)NN * D * 4);
    float* ar    = (float*)take((size_t)NN * 4);
    float* al    = (float*)take((size_t)NN * 4);
    unsigned long long* e_pack = (unsigned long long*)take((size_t)NE * 8);
    int*  basev  = (int*)  take((size_t)NN * 4);
    // zero-init region: counts, cursor, total (contiguous)
    size_t zero_begin = off;
    int*  counts = (int*)  take((size_t)NN * 4);
    int*  cursor = (int*)  take((size_t)NN * 4);
    int*  total  = (int*)  take(256);
    size_t zero_len = off - zero_begin;

    hipMemsetAsync(counts, 0, zero_len, stream);

    k1_node<<<2048, 256, 0, stream>>>(x, W1, W2, att_l, att_r, x_t, ar, al);
    k2_count<<<NE / 256, 256, 0, stream>>>(dst, counts);
    k3_alloc<<<(NN + 255) / 256, 256, 0, stream>>>(counts, basev, total);
    k4_fused<<<NE / 256, 256, 0, stream>>>(eattr, W1, att_l, src, dst, al, ar,
                                           basev, cursor, e_pack);
    k5_agg<<<(NN * D) / 256, 256, 0, stream>>>(x_t, e_pack, basev, counts,
                                               bias, gamma, beta, out);
}

// Round 4
// 472.980 us; speedup vs baseline: 1.2409x; 1.0923x over previous
//
#include <hip/hip_runtime.h>
#include <math.h>

// Problem constants (from reference)
#define NN 100000
#define NE 1600000
#define D 64
#define DE 16
#define NEG_SLOPE 0.01f
#define LN_EPS 1e-5f

// ---------- helpers ----------
__device__ __forceinline__ float wsum(float v) {
    #pragma unroll
    for (int d = 32; d > 0; d >>= 1) v += __shfl_xor(v, d, 64);
    return v;
}
__device__ __forceinline__ float wmaxr(float v) {
    #pragma unroll
    for (int d = 32; d > 0; d >>= 1) v = fmaxf(v, __shfl_xor(v, d, 64));
    return v;
}
__device__ __forceinline__ unsigned int f2u(float f) {
    union { float f; unsigned int u; } v; v.f = f; return v.u;
}
__device__ __forceinline__ float u2f(unsigned int u) {
    union { unsigned int u; float f; } v; v.u = u; return v.f;
}

// ---------- K1: per-node  x_t = x @ W2^T, ar = x.att_r, al = x.v1 ----------
// One wave per node. W2 row `lane` in 64 VGPRs; x row scalarized via
// readfirstlane so row[k] becomes s_load + v_fmac with SGPR operand
// (no ds_bpermute in the inner loop — that was the 60us LDS-pipe bottleneck).
__global__ __launch_bounds__(256) void k1_node(
        const float* __restrict__ x,
        const float* __restrict__ W1,
        const float* __restrict__ W2,
        const float* __restrict__ att_l,
        const float* __restrict__ att_r,
        float* __restrict__ x_t,
        float* __restrict__ ar,
        float* __restrict__ al)
{
    const int lane = threadIdx.x & 63;
    const int wid  = (blockIdx.x * blockDim.x + threadIdx.x) >> 6;
    const int nw   = (gridDim.x * blockDim.x) >> 6;

    // W2 row `lane` -> 64 VGPRs
    float w2r[D];
    {
        const float4* wr = reinterpret_cast<const float4*>(W2 + (size_t)lane * D);
        #pragma unroll
        for (int q = 0; q < 16; ++q) {
            float4 p = wr[q];
            w2r[q * 4 + 0] = p.x; w2r[q * 4 + 1] = p.y;
            w2r[q * 4 + 2] = p.z; w2r[q * 4 + 3] = p.w;
        }
    }
    // v1[lane] = sum_i att_l[i] * W1[i][lane]   (W1 is [64, 80] row-major)
    const float attr_j = att_r[lane];
    const float alv    = att_l[lane];
    float v1j = 0.f;
    for (int i = 0; i < D; ++i) {
        float ali = __shfl(alv, i, 64);
        v1j = fmaf(ali, W1[i * 80 + lane], v1j);
    }

    for (int n = wid; n < NN; n += nw) {
        // wave-uniform node index -> scalar loads of the x row
        const int nu = __builtin_amdgcn_readfirstlane(n);
        const float* __restrict__ row = x + (size_t)nu * D;

        // vector load for the attention dots (lane = k role)
        float xj = row[lane];

        // GEMM part (lane = f role): acc = sum_k row[k] * W2[f][k]
        float a0 = 0.f, a1 = 0.f, a2 = 0.f, a3 = 0.f;
        #pragma unroll
        for (int k = 0; k < D; k += 4) {
            a0 = fmaf(row[k + 0], w2r[k + 0], a0);
            a1 = fmaf(row[k + 1], w2r[k + 1], a1);
            a2 = fmaf(row[k + 2], w2r[k + 2], a2);
            a3 = fmaf(row[k + 3], w2r[k + 3], a3);
        }
        x_t[(size_t)nu * D + lane] = (a0 + a1) + (a2 + a3);

        float sr = wsum(xj * attr_j);
        float sl = wsum(xj * v1j);
        if (lane == 0) { ar[nu] = sr; al[nu] = sl; }
    }
}

// ---------- K2: per-edge degree histogram ----------
__global__ __launch_bounds__(256) void k2_count(
        const int* __restrict__ dst,
        int* __restrict__ counts)
{
    const int e = blockIdx.x * blockDim.x + threadIdx.x;  // exact grid
    atomicAdd(&counts[dst[e]], 1);
}

// ---------- K3: segment base allocation (wave scan + 1 atomic/wave) ----------
__global__ __launch_bounds__(256) void k3_alloc(
        const int* __restrict__ counts,
        int* __restrict__ basev,
        int* __restrict__ total)
{
    const int n = blockIdx.x * blockDim.x + threadIdx.x;
    const int lane = threadIdx.x & 63;
    int c = (n < NN) ? counts[n] : 0;
    int inc = c;
    #pragma unroll
    for (int dlt = 1; dlt < 64; dlt <<= 1) {
        int o = __shfl_up(inc, dlt, 64);
        if (lane >= dlt) inc += o;
    }
    int wtot = __shfl(inc, 63, 64);
    int wbase = 0;
    if (lane == 63) wbase = atomicAdd(total, wtot);
    wbase = __shfl(wbase, 63, 64);
    if (n < NN) basev[n] = wbase + inc - c;
}

// ---------- K4 (fused): e = leaky(al[src]+ar[dst]+ea.v2); scatter packed (e,src) ----------
__global__ __launch_bounds__(256) void k4_fused(
        const float* __restrict__ eattr,
        const float* __restrict__ W1,
        const float* __restrict__ att_l,
        const int* __restrict__ src,
        const int* __restrict__ dst,
        const float* __restrict__ al,
        const float* __restrict__ ar,
        const int* __restrict__ basev,
        int* __restrict__ cursor,
        unsigned long long* __restrict__ e_pack)
{
    __shared__ float als[D];
    __shared__ float v2s[DE];
    const int t = threadIdx.x;
    if (t < D) als[t] = att_l[t];
    __syncthreads();
    if (t < DE) {
        float a = 0.f;
        for (int i = 0; i < D; ++i)
            a = fmaf(als[i], W1[i * 80 + D + t], a);
        v2s[t] = a;
    }
    __syncthreads();
    float v2r[DE];
    #pragma unroll
    for (int j = 0; j < DE; ++j) v2r[j] = v2s[j];

    const int e = blockIdx.x * blockDim.x + t;   // exact grid NE/256
    int s = src[e], d = dst[e];
    float acc = al[s] + ar[d];
    const float4* ep = reinterpret_cast<const float4*>(eattr + (size_t)e * DE);
    #pragma unroll
    for (int q = 0; q < 4; ++q) {
        float4 p = ep[q];
        acc = fmaf(p.x, v2r[4 * q + 0], acc);
        acc = fmaf(p.y, v2r[4 * q + 1], acc);
        acc = fmaf(p.z, v2r[4 * q + 2], acc);
        acc = fmaf(p.w, v2r[4 * q + 3], acc);
    }
    float ev = acc > 0.f ? acc : NEG_SLOPE * acc;
    int pos = basev[d] + atomicAdd(&cursor[d], 1);
    unsigned long long pk = ((unsigned long long)(unsigned int)s << 32) |
                            (unsigned long long)f2u(ev);
    e_pack[pos] = pk;
}

// ---------- K5: per-node softmax + weighted aggregation + bias + LayerNorm ----------
__global__ __launch_bounds__(256) void k5_agg(
        const float* __restrict__ x_t,
        const unsigned long long* __restrict__ e_pack,
        const int* __restrict__ basev,
        const int* __restrict__ counts,
        const float* __restrict__ bias,
        const float* __restrict__ gamma,
        const float* __restrict__ beta,
        float* __restrict__ out)
{
    const int wid  = (blockIdx.x * blockDim.x + threadIdx.x) >> 6;  // node
    const int lane = threadIdx.x & 63;                              // feature
    if (wid >= NN) return;
    const int base = basev[wid];
    const int cnt  = counts[wid];

    float m = -1e30f;
    for (int i = lane; i < cnt; i += 64)
        m = fmaxf(m, u2f((unsigned int)e_pack[base + i]));
    m = wmaxr(m);
    float ssum = 0.f;
    for (int i = lane; i < cnt; i += 64)
        ssum += __expf(u2f((unsigned int)e_pack[base + i]) - m);
    ssum = wsum(ssum);
    const float inv = (cnt > 0) ? 1.f / ssum : 0.f;

    float acc0 = 0.f, acc1 = 0.f;
    for (int c0 = 0; c0 < cnt; c0 += 64) {
        int i = c0 + lane;
        float av = 0.f; int sv = 0;
        if (i < cnt) {
            unsigned long long pk = e_pack[base + i];
            av = __expf(u2f((unsigned int)pk) - m) * inv;
            sv = (int)(pk >> 32);
        }
        int lim = min(64, cnt - c0);
        int j = 0;
        for (; j + 1 < lim; j += 2) {
            float aj0 = __shfl(av, j, 64);
            int   sj0 = __shfl(sv, j, 64);
            float aj1 = __shfl(av, j + 1, 64);
            int   sj1 = __shfl(sv, j + 1, 64);
            float v0 = x_t[(size_t)sj0 * D + lane];
            float v1 = x_t[(size_t)sj1 * D + lane];
            acc0 = fmaf(aj0, v0, acc0);
            acc1 = fmaf(aj1, v1, acc1);
        }
        if (j < lim) {
            float aj = __shfl(av, j, 64);
            int   sj = __shfl(sv, j, 64);
            acc0 = fmaf(aj, x_t[(size_t)sj * D + lane], acc0);
        }
    }
    float h  = acc0 + acc1 + bias[lane];
    float mu = wsum(h) * (1.f / 64.f);
    float dd = h - mu;
    float var = wsum(dd * dd) * (1.f / 64.f);
    float o = dd * rsqrtf(var + LN_EPS) * gamma[lane] + beta[lane];
    out[(size_t)wid * D + lane] = o;
}

// ---------- launch ----------
extern "C" void kernel_launch(void* const* d_in, const int* in_sizes, int n_in,
                              void* d_out, int out_size, void* d_ws, size_t ws_size,
                              hipStream_t stream) {
    const float* x     = (const float*)d_in[0];
    const float* eattr = (const float*)d_in[1];
    const float* W1    = (const float*)d_in[2];
    const float* W2    = (const float*)d_in[3];
    const float* att_l = (const float*)d_in[4];
    const float* att_r = (const float*)d_in[5];
    const float* bias  = (const float*)d_in[6];
    const float* gamma = (const float*)d_in[7];
    const float* beta  = (const float*)d_in[8];
    const int* src = (const int*)d_in[9];
    const int* dst = (const int*)d_in[10];
    float* out = (float*)d_out;

    // workspace layout (256B aligned chunks)
    char* p = (char*)d_ws;
    size_t off = 0;
    auto take = [&](size_t bytes) {
        void* q = p + off;
        off += (bytes + 255) & ~(size_t)255;
        return q;
    };
    float* x_t   = (float*)take((size_t)NN * D * 4);
    float* ar    = (float*)take((size_t)NN * 4);
    float* al    = (float*)take((size_t)NN * 4);
    unsigned long long* e_pack = (unsigned long long*)take((size_t)NE * 8);
    int*  basev  = (int*)  take((size_t)NN * 4);
    // zero-init region: counts, cursor, total (contiguous)
    size_t zero_begin = off;
    int*  counts = (int*)  take((size_t)NN * 4);
    int*  cursor = (int*)  take((size_t)NN * 4);
    int*  total  = (int*)  take(256);
    size_t zero_len = off - zero_begin;

    hipMemsetAsync(counts, 0, zero_len, stream);

    k1_node<<<2048, 256, 0, stream>>>(x, W1, W2, att_l, att_r, x_t, ar, al);
    k2_count<<<NE / 256, 256, 0, stream>>>(dst, counts);
    k3_alloc<<<(NN + 255) / 256, 256, 0, stream>>>(counts, basev, total);
    k4_fused<<<NE / 256, 256, 0, stream>>>(eattr, W1, att_l, src, dst, al, ar,
                                           basev, cursor, e_pack);
    k5_agg<<<(NN * D) / 256, 256, 0, stream>>>(x_t, e_pack, basev, counts,
                                               bias, gamma, beta, out);
}